// Round 5
// baseline (406.287 us; speedup 1.0000x reference)
//
#include <hip/hip_runtime.h>

// RelationLayer, round 5. All fp32 (threshold 8*eps_fp32 forbids bf16 MFMA;
// no fp32 MFMA on CDNA4 -> VALU GEMMs).
//
// R5 change: pair_kernel restructured to remove the LDS-throughput ceiling.
// Old: tx/ty 8x8 reg tiles, 4x ds_read_b128 per 64 FMA -> LDS pipe 384cyc vs
// VALU 256cyc per CU-step -> 67% VALU ceiling (measured 57%).
// New: lane=row. Wave w covers rows 64*(w&1), cols 64*(w>>1); acc[64]/thread.
// Per cc: ONE ds_read_b32 (a[row][cc], conflict-free) + 64 v_fmac with the
// weight operand WAVE-UNIFORM -> s_load (SMEM pipe; col base laundered via
// readfirstlane). LDS load per CU-step ~46cyc vs VALU 256cyc -> VALU-bound.
// Al is plain column-major [c][r] 64KB (2 blocks/CU), no swizzle needed:
// every access has lane=row stride-1 (<=2-way, free). j-mean via __shfl_xor
// butterfly (63 shfl+add, no LDS); barriers: 5/block vs ~50.
//
// Pipeline:
//  conv  : ONE uniform GEMM 2048x640x512 (win1 + 3 win3 tap partials).
//          Recombination y3[row]=G0[row-32]+G1[row]+G2[row+32] in stats/ab.
//          Conv bias skipped: BN subtracts the mean, bias cancels exactly.
//  stats : per-channel mean/var -> scale/shift (folds BN + gamma/beta).
//  ab    : h = leaky(y*scale+shift)*mask on the fly; a=h@w0[:C], bb=h@w0[C:].
//  pair  : above. -> pmean
//  out   : pmean -> leaky(@w4+b4) -> leaky(@w5+b5)*mask.

#define BB 32
#define CCH 384

__device__ __forceinline__ float leaky(float x) { return fmaxf(x, 0.1f * x); }

// ---------------------------------------------------------------- conv ------
// grid 320 = 64 row-tiles(32) x 5 col-groups(128). Uniform GEMM blocks.
__global__ __launch_bounds__(256) void conv_kernel(
    const float* __restrict__ x, const float* __restrict__ mask,
    const float* __restrict__ cw0, const float* __restrict__ cw1,
    float* __restrict__ yG)
{
  __shared__ float As[32 * 36];    // [k][r]
  __shared__ float Ws[32 * 132];   // [k][c]
  int bx = blockIdx.x;
  int rt = bx & 63;        // row tile (one l, 32 b's)
  int ct = bx >> 6;        // col group 0..4
  int row0 = rt * 32;
  int tid = threadIdx.x;

  const float* wbase; int wstride;
  if (ct < 2) { wbase = cw0 + ct * 128 * 512; wstride = 512; }
  else        { wbase = cw1 + (ct - 2) * 512; wstride = 1536; }

  int sr  = tid >> 3;            // row 0..31
  int sk4 = (tid & 7) * 4;       // k offset 0..28
  const float* xrow = x + (row0 + sr) * 512;
  float mval = mask[row0 + sr];

  int r4 = (tid >> 5) * 4;
  int c4 = (tid & 31) * 4;

  float acc[4][4] = {{0.f,0.f,0.f,0.f},{0.f,0.f,0.f,0.f},
                     {0.f,0.f,0.f,0.f},{0.f,0.f,0.f,0.f}};
#pragma unroll 1
  for (int k0 = 0; k0 < 512; k0 += 32) {
    float4 xv = *(const float4*)(xrow + k0 + sk4);
    float4 wv[4];
#pragma unroll
    for (int rep = 0; rep < 4; ++rep) {
      int slot = rep * 256 + tid;
      int c = slot >> 3;               // 0..127
      int kq4 = (slot & 7) * 4;        // lanes contiguous along k
      wv[rep] = *(const float4*)(wbase + c * wstride + k0 + kq4);
    }
    __syncthreads();
    As[(sk4 + 0) * 36 + sr] = xv.x * mval;
    As[(sk4 + 1) * 36 + sr] = xv.y * mval;
    As[(sk4 + 2) * 36 + sr] = xv.z * mval;
    As[(sk4 + 3) * 36 + sr] = xv.w * mval;
#pragma unroll
    for (int rep = 0; rep < 4; ++rep) {
      int slot = rep * 256 + tid;
      int c = slot >> 3;
      int kq4 = (slot & 7) * 4;
      Ws[(kq4 + 0) * 132 + c] = wv[rep].x;
      Ws[(kq4 + 1) * 132 + c] = wv[rep].y;
      Ws[(kq4 + 2) * 132 + c] = wv[rep].z;
      Ws[(kq4 + 3) * 132 + c] = wv[rep].w;
    }
    __syncthreads();
#pragma unroll
    for (int kk = 0; kk < 32; ++kk) {
      float4 a = *(const float4*)&As[kk * 36 + r4];
      float4 w = *(const float4*)&Ws[kk * 132 + c4];
      float av[4] = {a.x, a.y, a.z, a.w};
      float wv2[4] = {w.x, w.y, w.z, w.w};
#pragma unroll
      for (int ri = 0; ri < 4; ++ri)
#pragma unroll
        for (int ci = 0; ci < 4; ++ci)
          acc[ri][ci] = fmaf(av[ri], wv2[ci], acc[ri][ci]);
    }
  }
#pragma unroll
  for (int ci = 0; ci < 4; ++ci)
    *(float4*)&yG[(ct * 128 + c4 + ci) * 2048 + row0 + r4] =
        make_float4(acc[0][ci], acc[1][ci], acc[2][ci], acc[3][ci]);
}

// --------------------------------------------------------------- stats ------
__global__ __launch_bounds__(256) void stats_kernel(
    const float* __restrict__ yG,
    const float* __restrict__ g0, const float* __restrict__ be0,
    const float* __restrict__ g1, const float* __restrict__ be1,
    float* __restrict__ scale, float* __restrict__ shift)
{
  int c = blockIdx.x;
  int tid = threadIdx.x;
  float s = 0.f, s2 = 0.f;
  if (c < 256) {
    const float* src = yG + c * 2048 + tid * 8;
    float4 v0 = *(const float4*)(src);
    float4 v1 = *(const float4*)(src + 4);
    s  = v0.x + v0.y + v0.z + v0.w + v1.x + v1.y + v1.z + v1.w;
    s2 = v0.x*v0.x + v0.y*v0.y + v0.z*v0.z + v0.w*v0.w
       + v1.x*v1.x + v1.y*v1.y + v1.z*v1.z + v1.w*v1.w;
  } else {
    int cc = c - 256;
    const float* p0 = yG + (256 + cc) * 2048;
    const float* p1 = yG + (384 + cc) * 2048;
    const float* p2 = yG + (512 + cc) * 2048;
#pragma unroll
    for (int j = 0; j < 8; ++j) {
      int e = tid * 8 + j;
      float v = p1[e];
      if (e >= 32)   v += p0[e - 32];
      if (e < 2016)  v += p2[e + 32];
      s += v; s2 += v * v;
    }
  }
#pragma unroll
  for (int off = 32; off > 0; off >>= 1) {
    s  += __shfl_down(s, off);
    s2 += __shfl_down(s2, off);
  }
  __shared__ float rs[4], rs2[4];
  int wid = tid >> 6;
  if ((tid & 63) == 0) { rs[wid] = s; rs2[wid] = s2; }
  __syncthreads();
  if (tid == 0) {
    float S  = rs[0] + rs[1] + rs[2] + rs[3];
    float S2 = rs2[0] + rs2[1] + rs2[2] + rs2[3];
    float mean = S * (1.f / 2048.f);
    float var  = S2 * (1.f / 2048.f) - mean * mean;
    float g  = (c < 256) ? g0[c] : g1[c - 256];
    float be = (c < 256) ? be0[c] : be1[c - 256];
    float sc = g / sqrtf(var + 1e-5f);
    scale[c] = sc;
    shift[c] = be - mean * sc;
  }
}

// ------------------------------------------------------------------ ab ------
// grid 256 = 64 row-tiles(32) x 4 col-tiles(64).
__global__ __launch_bounds__(256) void ab_kernel(
    const float* __restrict__ yG, const float* __restrict__ scale,
    const float* __restrict__ shift, const float* __restrict__ mask,
    const float* __restrict__ w0,
    float* __restrict__ a_arr, float* __restrict__ bb_arr)
{
  __shared__ float As[32 * 36];
  __shared__ float Ws[32 * 68];
  int bx = blockIdx.x;
  int rt = bx & 63, ct = bx >> 6;
  int row0 = rt * 32, n0 = ct * 64;
  int tid = threadIdx.x;
  int r4 = (tid >> 5) * 4;
  int n2 = (tid & 31) * 2;
  int scc = tid >> 3, srr4 = (tid & 7) * 4;
  int wnn8 = (tid & 7) * 8;
  const float* wbase = (n0 < 128) ? (w0 + n0) : (w0 + CCH * 128 + (n0 - 128));
  float4 mv = *(const float4*)(mask + row0 + srr4);

  float acc[4][2] = {{0.f, 0.f}};
#pragma unroll 1
  for (int c0 = 0; c0 < 384; c0 += 32) {
    int c = c0 + scc;
    float4 yv;
    if (c < 256) {
      yv = *(const float4*)(yG + c * 2048 + row0 + srr4);
    } else {
      int cc = c - 256;
      yv = *(const float4*)(yG + (384 + cc) * 2048 + row0 + srr4);
      if (rt > 0) {
        float4 u = *(const float4*)(yG + (256 + cc) * 2048 + row0 + srr4 - 32);
        yv.x += u.x; yv.y += u.y; yv.z += u.z; yv.w += u.w;
      }
      if (rt < 63) {
        float4 u = *(const float4*)(yG + (512 + cc) * 2048 + row0 + srr4 + 32);
        yv.x += u.x; yv.y += u.y; yv.z += u.z; yv.w += u.w;
      }
    }
    float sc = scale[c], sh = shift[c];
    float4 wv0 = *(const float4*)(wbase + c * 128 + wnn8);
    float4 wv1 = *(const float4*)(wbase + c * 128 + wnn8 + 4);
    __syncthreads();
    float4 hv;
    hv.x = leaky(fmaf(yv.x, sc, sh)) * mv.x;
    hv.y = leaky(fmaf(yv.y, sc, sh)) * mv.y;
    hv.z = leaky(fmaf(yv.z, sc, sh)) * mv.z;
    hv.w = leaky(fmaf(yv.w, sc, sh)) * mv.w;
    *(float4*)&As[scc * 36 + srr4] = hv;
    *(float4*)&Ws[scc * 68 + wnn8] = wv0;
    *(float4*)&Ws[scc * 68 + wnn8 + 4] = wv1;
    __syncthreads();
#pragma unroll
    for (int cc = 0; cc < 32; ++cc) {
      float4 a = *(const float4*)&As[cc * 36 + r4];
      float2 w = *(const float2*)&Ws[cc * 68 + n2];
      acc[0][0] = fmaf(a.x, w.x, acc[0][0]); acc[0][1] = fmaf(a.x, w.y, acc[0][1]);
      acc[1][0] = fmaf(a.y, w.x, acc[1][0]); acc[1][1] = fmaf(a.y, w.y, acc[1][1]);
      acc[2][0] = fmaf(a.z, w.x, acc[2][0]); acc[2][1] = fmaf(a.z, w.y, acc[2][1]);
      acc[3][0] = fmaf(a.w, w.x, acc[3][0]); acc[3][1] = fmaf(a.w, w.y, acc[3][1]);
    }
  }
  float* dst; int nd;
  if (n0 < 128) { dst = a_arr; nd = n0; } else { dst = bb_arr; nd = n0 - 128; }
#pragma unroll
  for (int ri = 0; ri < 4; ++ri)
    *(float2*)&dst[(row0 + r4 + ri) * 128 + nd + n2] = make_float2(acc[ri][0], acc[ri][1]);
}

// ---------------------------------------------------------------- pair ------
// grid (64,16), 256 threads = 4 waves. Wave w: rows 64*(w&1)+lane, cols
// 64*(w>>1)..+63. Al column-major [c][r], 64KB -> 2 blocks/CU.
// Weights read wave-uniformly (s_load path); a via 1 ds_read_b32/cc.
__global__ __launch_bounds__(256) void pair_kernel(
    const float* __restrict__ a_arr, const float* __restrict__ bb_arr,
    const float* __restrict__ b0,
    const float* __restrict__ w1, const float* __restrict__ b1,
    const float* __restrict__ w2, const float* __restrict__ b2,
    const float* __restrict__ w3, const float* __restrict__ b3,
    const float* __restrict__ mask, float* __restrict__ pmean)
{
  __shared__ float Al[128 * 128];   // [c][r], plain column-major
  int i = blockIdx.x, bp = blockIdx.y;
  int tid = threadIdx.x;
  int lane = tid & 63;
  // laundered wave id -> provably wave-uniform col/row bases (enables s_load)
  int widu = __builtin_amdgcn_readfirstlane(tid >> 6);
  int rb = (widu & 1) * 64;          // row base (db)
  int cb = (widu >> 1) * 64;         // col base
  int b  = bp * 2 + (widu & 1);      // batch (uniform per wave)
  int row = rb + lane;
  int brow = i * BB + b;             // uniform

  // ---- init: p0 = leaky(a_i + bb_j + b0); lane=j=row&63 ----
  {
    const float* ai  = a_arr + brow * 128 + cb;           // uniform row
    const float* bz  = b0 + cb;                           // uniform
    const float* bbr = bb_arr + (lane * BB + b) * 128 + cb;  // per-lane row
#pragma unroll
    for (int q = 0; q < 16; ++q) {
      float4 bv = *(const float4*)(bbr + 4 * q);
      float4 av = *(const float4*)(ai + 4 * q);
      float4 zv = *(const float4*)(bz + 4 * q);
      int c = cb + 4 * q;
      Al[(c + 0) * 128 + row] = leaky(av.x + bv.x + zv.x);
      Al[(c + 1) * 128 + row] = leaky(av.y + bv.y + zv.y);
      Al[(c + 2) * 128 + row] = leaky(av.z + bv.z + zv.z);
      Al[(c + 3) * 128 + row] = leaky(av.w + bv.w + zv.w);
    }
  }
  __syncthreads();

  float acc[64];
#pragma unroll 1
  for (int layer = 0; layer < 3; ++layer) {
    const float* W  = (layer == 0) ? w1 : (layer == 1) ? w2 : w3;
    const float* Bv = (layer == 0) ? b1 : (layer == 1) ? b2 : b3;
#pragma unroll
    for (int v = 0; v < 64; ++v) acc[v] = 0.f;
#pragma unroll 1
    for (int cc = 0; cc < 128; ++cc) {
      float av = Al[cc * 128 + row];          // 1 ds_read_b32, conflict-free
      const float* wr = W + cc * 128 + cb;    // wave-uniform -> s_load
#pragma unroll
      for (int v = 0; v < 64; ++v)
        acc[v] = fmaf(av, wr[v], acc[v]);
    }
    const float* bc = Bv + cb;                // uniform
#pragma unroll
    for (int v = 0; v < 64; ++v) acc[v] = leaky(acc[v] + bc[v]);
    if (layer < 2) {
      __syncthreads();                        // all reads of Al done
#pragma unroll
      for (int v = 0; v < 64; ++v)
        Al[(cb + v) * 128 + row] = acc[v];    // transposed wb, conflict-free
      __syncthreads();
    }
  }

  // ---- j-mean: butterfly over the 64 lanes (lane==j). After the tree,
  // acc[0] = sum_j p[.., col = cb + lane]. ----
#pragma unroll
  for (int o = 32; o >= 1; o >>= 1) {
#pragma unroll
    for (int t = 0; t < 64; ++t) {
      if (t >= o) break;  // (unrolled: compiles away; bounds o known)
      bool up = (lane & o) != 0;
      float send = up ? acc[t] : acc[o + t];
      float keep = up ? acc[o + t] : acc[t];
      acc[t] = keep + __shfl_xor(send, o, 64);
    }
  }
  pmean[brow * 128 + cb + lane] = acc[0] * (1.0f / 64.0f) * mask[brow];
}

// ----------------------------------------------------------------- out ------
// grid 256 = 128 row-tiles(16) x 2 col-tiles(256)
__global__ __launch_bounds__(256) void out_kernel(
    const float* __restrict__ pmean, const float* __restrict__ w4,
    const float* __restrict__ b4, const float* __restrict__ w5,
    const float* __restrict__ b5, const float* __restrict__ mask,
    float* __restrict__ out)
{
  __shared__ float Pm[16 * 132];
  __shared__ float T4[16 * 132];
  int bx = blockIdx.x;
  int col0 = (bx & 1) * 256;
  int row0 = (bx >> 1) * 16;
  int tid = threadIdx.x;
  int tr = tid >> 4, m = tid & 15;

  {
    const float* src = pmean + (row0 + tr) * 128 + 8 * m;
    *(float4*)&Pm[tr * 132 + 8 * m]     = *(const float4*)(src);
    *(float4*)&Pm[tr * 132 + 8 * m + 4] = *(const float4*)(src + 4);
  }
  __syncthreads();
  {
    int k8 = m * 8;
    float4 bv0 = *(const float4*)(b4 + k8);
    float4 bv1 = *(const float4*)(b4 + k8 + 4);
    float t[8] = {bv0.x, bv0.y, bv0.z, bv0.w, bv1.x, bv1.y, bv1.z, bv1.w};
#pragma unroll 4
    for (int cc = 0; cc < 128; ++cc) {
      float a = Pm[tr * 132 + cc];
      float4 w0v = *(const float4*)(w4 + cc * 128 + k8);
      float4 w1v = *(const float4*)(w4 + cc * 128 + k8 + 4);
      t[0] = fmaf(a, w0v.x, t[0]); t[1] = fmaf(a, w0v.y, t[1]);
      t[2] = fmaf(a, w0v.z, t[2]); t[3] = fmaf(a, w0v.w, t[3]);
      t[4] = fmaf(a, w1v.x, t[4]); t[5] = fmaf(a, w1v.y, t[5]);
      t[6] = fmaf(a, w1v.z, t[6]); t[7] = fmaf(a, w1v.w, t[7]);
    }
    *(float4*)&T4[tr * 132 + k8]     = make_float4(leaky(t[0]), leaky(t[1]), leaky(t[2]), leaky(t[3]));
    *(float4*)&T4[tr * 132 + k8 + 4] = make_float4(leaky(t[4]), leaky(t[5]), leaky(t[6]), leaky(t[7]));
  }
  __syncthreads();
  {
    int c16 = m * 16;
    const float* bsrc = b5 + col0 + c16;
    float o[16];
#pragma unroll
    for (int q = 0; q < 4; ++q) {
      float4 bv = *(const float4*)(bsrc + 4 * q);
      o[4*q+0] = bv.x; o[4*q+1] = bv.y; o[4*q+2] = bv.z; o[4*q+3] = bv.w;
    }
#pragma unroll 2
    for (int cc = 0; cc < 128; ++cc) {
      float a = T4[tr * 132 + cc];
      const float* wr = w5 + cc * 512 + col0 + c16;
#pragma unroll
      for (int q = 0; q < 4; ++q) {
        float4 wv = *(const float4*)(wr + 4 * q);
        o[4*q+0] = fmaf(a, wv.x, o[4*q+0]);
        o[4*q+1] = fmaf(a, wv.y, o[4*q+1]);
        o[4*q+2] = fmaf(a, wv.z, o[4*q+2]);
        o[4*q+3] = fmaf(a, wv.w, o[4*q+3]);
      }
    }
    float mv = mask[row0 + tr];
    float* dst = out + (row0 + tr) * 512 + col0 + c16;
#pragma unroll
    for (int q = 0; q < 4; ++q)
      *(float4*)(dst + 4 * q) = make_float4(leaky(o[4*q+0]) * mv, leaky(o[4*q+1]) * mv,
                                            leaky(o[4*q+2]) * mv, leaky(o[4*q+3]) * mv);
  }
}

// -------------------------------------------------------------- launch ------
extern "C" void kernel_launch(void* const* d_in, const int* in_sizes, int n_in,
                              void* d_out, int out_size, void* d_ws, size_t ws_size,
                              hipStream_t stream) {
  const float* x    = (const float*)d_in[0];
  const float* mask = (const float*)d_in[1];
  const float* cw0  = (const float*)d_in[2];
  // d_in[3] conv_b0: cancels in BN
  const float* g0   = (const float*)d_in[4];
  const float* be0  = (const float*)d_in[5];
  const float* cw1  = (const float*)d_in[6];
  // d_in[7] conv_b1: cancels in BN
  const float* g1   = (const float*)d_in[8];
  const float* be1  = (const float*)d_in[9];
  const float* w0   = (const float*)d_in[10];
  const float* b0   = (const float*)d_in[11];
  const float* w1   = (const float*)d_in[12];
  const float* b1   = (const float*)d_in[13];
  const float* w2   = (const float*)d_in[14];
  const float* b2   = (const float*)d_in[15];
  const float* w3   = (const float*)d_in[16];
  const float* b3   = (const float*)d_in[17];
  const float* w4   = (const float*)d_in[18];
  const float* b4   = (const float*)d_in[19];
  const float* w5   = (const float*)d_in[20];
  const float* b5   = (const float*)d_in[21];

  float* ws     = (float*)d_ws;
  float* yG     = ws;                    // 640*2048 = 1,310,720
  float* pmean  = ws;                    // overlays yG (yG dead after ab)
  float* scale  = ws + 1310720;          // 384
  float* shift  = ws + 1311104;          // 384
  float* a_arr  = ws + 1311488;          // 2048*128
  float* bb_arr = ws + 1573632;          // 2048*128
  float* outp   = (float*)d_out;

  conv_kernel<<<320, 256, 0, stream>>>(x, mask, cw0, cw1, yG);
  stats_kernel<<<384, 256, 0, stream>>>(yG, g0, be0, g1, be1, scale, shift);
  ab_kernel<<<256, 256, 0, stream>>>(yG, scale, shift, mask, w0, a_arr, bb_arr);
  dim3 g5(64, 16);
  pair_kernel<<<g5, 256, 0, stream>>>(a_arr, bb_arr, b0, w1, b1, w2, b2, w3, b3,
                                      mask, pmean);
  out_kernel<<<256, 256, 0, stream>>>(pmean, w4, b4, w5, b5, mask, outp);
}

// Round 6
// 295.561 us; speedup vs baseline: 1.3746x; 1.3746x over previous
//
#include <hip/hip_runtime.h>

// RelationLayer, round 6.
// pair_kernel moved to MATRIX cores via fp16 two-term splitting:
//   x = xh + xl  (xh = fp16(x), xl = fp16((x-xh)*2048) -- scaled to stay
//   normal-range, avoiding potential MFMA denorm flush), same for W.
//   D = sum xh*wh  +  (1/2048) * sum (xh*wl' + xl'*wh);  xl*wl (~2^-22) dropped.
// All products are exact in fp32-accumulating MFMA -> fp32-grade accuracy
// (predicted absmax ~1e-6 vs threshold 3.76e-6). 3 MFMA products -> ~800 TF
// effective vs the 157 TF fp32 VALU ceiling that capped R1-R5.
// Per block: 128x128 tile; 4 waves 2x2, each 64x64 = 4x4 C-frags of
// mfma_f32_16x16x32_f16, two acc sets (hi + cross). A packed (hi|lo) in one
// u32 word in LDS (read once, serves both products); W pre-split/transposed
// by wsplit into wpk[L][n][k] and read as B-frags straight from L2.
// Layouts (verified m89/m91/m120): A: m=lane&15, k=quad*8+j;
// B: n=lane&15, k=quad*8+j; C/D: col=lane&15, row=quad*4+reg.
//
// conv/stats/ab/out unchanged from R4 for attribution.

#define BB 32
#define CCH 384

__device__ __forceinline__ float leaky(float x) { return fmaxf(x, 0.1f * x); }

typedef _Float16 f16x8 __attribute__((ext_vector_type(8)));
typedef float f32x4 __attribute__((ext_vector_type(4)));

union F8u { uint32_t u[4]; uint4 q; f16x8 h; };

__device__ __forceinline__ uint32_t pack2(float x) {
  _Float16 hi = (_Float16)x;
  _Float16 lo = (_Float16)((x - (float)hi) * 2048.0f);
  union { _Float16 f[2]; uint32_t u; } p;
  p.f[0] = hi; p.f[1] = lo;
  return p.u;
}

#define SEL_LO 0x05040100u  // (w0.lo16, w1.lo16) -> hi-part pair (stored low)
#define SEL_HI 0x07060302u  // (w0.hi16, w1.hi16) -> lo-part pair (stored high)

// ---------------------------------------------------------------- conv ------
__global__ __launch_bounds__(256) void conv_kernel(
    const float* __restrict__ x, const float* __restrict__ mask,
    const float* __restrict__ cw0, const float* __restrict__ cw1,
    float* __restrict__ yG)
{
  __shared__ float As[32 * 36];
  __shared__ float Ws[32 * 132];
  int bx = blockIdx.x;
  int rt = bx & 63;
  int ct = bx >> 6;
  int row0 = rt * 32;
  int tid = threadIdx.x;

  const float* wbase; int wstride;
  if (ct < 2) { wbase = cw0 + ct * 128 * 512; wstride = 512; }
  else        { wbase = cw1 + (ct - 2) * 512; wstride = 1536; }

  int sr  = tid >> 3;
  int sk4 = (tid & 7) * 4;
  const float* xrow = x + (row0 + sr) * 512;
  float mval = mask[row0 + sr];

  int r4 = (tid >> 5) * 4;
  int c4 = (tid & 31) * 4;

  float acc[4][4] = {{0.f,0.f,0.f,0.f},{0.f,0.f,0.f,0.f},
                     {0.f,0.f,0.f,0.f},{0.f,0.f,0.f,0.f}};
#pragma unroll 1
  for (int k0 = 0; k0 < 512; k0 += 32) {
    float4 xv = *(const float4*)(xrow + k0 + sk4);
    float4 wv[4];
#pragma unroll
    for (int rep = 0; rep < 4; ++rep) {
      int slot = rep * 256 + tid;
      int c = slot >> 3;
      int kq4 = (slot & 7) * 4;
      wv[rep] = *(const float4*)(wbase + c * wstride + k0 + kq4);
    }
    __syncthreads();
    As[(sk4 + 0) * 36 + sr] = xv.x * mval;
    As[(sk4 + 1) * 36 + sr] = xv.y * mval;
    As[(sk4 + 2) * 36 + sr] = xv.z * mval;
    As[(sk4 + 3) * 36 + sr] = xv.w * mval;
#pragma unroll
    for (int rep = 0; rep < 4; ++rep) {
      int slot = rep * 256 + tid;
      int c = slot >> 3;
      int kq4 = (slot & 7) * 4;
      Ws[(kq4 + 0) * 132 + c] = wv[rep].x;
      Ws[(kq4 + 1) * 132 + c] = wv[rep].y;
      Ws[(kq4 + 2) * 132 + c] = wv[rep].z;
      Ws[(kq4 + 3) * 132 + c] = wv[rep].w;
    }
    __syncthreads();
#pragma unroll
    for (int kk = 0; kk < 32; ++kk) {
      float4 a = *(const float4*)&As[kk * 36 + r4];
      float4 w = *(const float4*)&Ws[kk * 132 + c4];
      float av[4] = {a.x, a.y, a.z, a.w};
      float wv2[4] = {w.x, w.y, w.z, w.w};
#pragma unroll
      for (int ri = 0; ri < 4; ++ri)
#pragma unroll
        for (int ci = 0; ci < 4; ++ci)
          acc[ri][ci] = fmaf(av[ri], wv2[ci], acc[ri][ci]);
    }
  }
#pragma unroll
  for (int ci = 0; ci < 4; ++ci)
    *(float4*)&yG[(ct * 128 + c4 + ci) * 2048 + row0 + r4] =
        make_float4(acc[0][ci], acc[1][ci], acc[2][ci], acc[3][ci]);
}

// --------------------------------------------------------------- stats ------
__global__ __launch_bounds__(256) void stats_kernel(
    const float* __restrict__ yG,
    const float* __restrict__ g0, const float* __restrict__ be0,
    const float* __restrict__ g1, const float* __restrict__ be1,
    float* __restrict__ scale, float* __restrict__ shift)
{
  int c = blockIdx.x;
  int tid = threadIdx.x;
  float s = 0.f, s2 = 0.f;
  if (c < 256) {
    const float* src = yG + c * 2048 + tid * 8;
    float4 v0 = *(const float4*)(src);
    float4 v1 = *(const float4*)(src + 4);
    s  = v0.x + v0.y + v0.z + v0.w + v1.x + v1.y + v1.z + v1.w;
    s2 = v0.x*v0.x + v0.y*v0.y + v0.z*v0.z + v0.w*v0.w
       + v1.x*v1.x + v1.y*v1.y + v1.z*v1.z + v1.w*v1.w;
  } else {
    int cc = c - 256;
    const float* p0 = yG + (256 + cc) * 2048;
    const float* p1 = yG + (384 + cc) * 2048;
    const float* p2 = yG + (512 + cc) * 2048;
#pragma unroll
    for (int j = 0; j < 8; ++j) {
      int e = tid * 8 + j;
      float v = p1[e];
      if (e >= 32)   v += p0[e - 32];
      if (e < 2016)  v += p2[e + 32];
      s += v; s2 += v * v;
    }
  }
#pragma unroll
  for (int off = 32; off > 0; off >>= 1) {
    s  += __shfl_down(s, off);
    s2 += __shfl_down(s2, off);
  }
  __shared__ float rs[4], rs2[4];
  int wid = tid >> 6;
  if ((tid & 63) == 0) { rs[wid] = s; rs2[wid] = s2; }
  __syncthreads();
  if (tid == 0) {
    float S  = rs[0] + rs[1] + rs[2] + rs[3];
    float S2 = rs2[0] + rs2[1] + rs2[2] + rs2[3];
    float mean = S * (1.f / 2048.f);
    float var  = S2 * (1.f / 2048.f) - mean * mean;
    float g  = (c < 256) ? g0[c] : g1[c - 256];
    float be = (c < 256) ? be0[c] : be1[c - 256];
    float sc = g / sqrtf(var + 1e-5f);
    scale[c] = sc;
    shift[c] = be - mean * sc;
  }
}

// ------------------------------------------------------------------ ab ------
__global__ __launch_bounds__(256) void ab_kernel(
    const float* __restrict__ yG, const float* __restrict__ scale,
    const float* __restrict__ shift, const float* __restrict__ mask,
    const float* __restrict__ w0,
    float* __restrict__ a_arr, float* __restrict__ bb_arr)
{
  __shared__ float As[32 * 36];
  __shared__ float Ws[32 * 68];
  int bx = blockIdx.x;
  int rt = bx & 63, ct = bx >> 6;
  int row0 = rt * 32, n0 = ct * 64;
  int tid = threadIdx.x;
  int r4 = (tid >> 5) * 4;
  int n2 = (tid & 31) * 2;
  int scc = tid >> 3, srr4 = (tid & 7) * 4;
  int wnn8 = (tid & 7) * 8;
  const float* wbase = (n0 < 128) ? (w0 + n0) : (w0 + CCH * 128 + (n0 - 128));
  float4 mv = *(const float4*)(mask + row0 + srr4);

  float acc[4][2] = {{0.f, 0.f}};
#pragma unroll 1
  for (int c0 = 0; c0 < 384; c0 += 32) {
    int c = c0 + scc;
    float4 yv;
    if (c < 256) {
      yv = *(const float4*)(yG + c * 2048 + row0 + srr4);
    } else {
      int cc = c - 256;
      yv = *(const float4*)(yG + (384 + cc) * 2048 + row0 + srr4);
      if (rt > 0) {
        float4 u = *(const float4*)(yG + (256 + cc) * 2048 + row0 + srr4 - 32);
        yv.x += u.x; yv.y += u.y; yv.z += u.z; yv.w += u.w;
      }
      if (rt < 63) {
        float4 u = *(const float4*)(yG + (512 + cc) * 2048 + row0 + srr4 + 32);
        yv.x += u.x; yv.y += u.y; yv.z += u.z; yv.w += u.w;
      }
    }
    float sc = scale[c], sh = shift[c];
    float4 wv0 = *(const float4*)(wbase + c * 128 + wnn8);
    float4 wv1 = *(const float4*)(wbase + c * 128 + wnn8 + 4);
    __syncthreads();
    float4 hv;
    hv.x = leaky(fmaf(yv.x, sc, sh)) * mv.x;
    hv.y = leaky(fmaf(yv.y, sc, sh)) * mv.y;
    hv.z = leaky(fmaf(yv.z, sc, sh)) * mv.z;
    hv.w = leaky(fmaf(yv.w, sc, sh)) * mv.w;
    *(float4*)&As[scc * 36 + srr4] = hv;
    *(float4*)&Ws[scc * 68 + wnn8] = wv0;
    *(float4*)&Ws[scc * 68 + wnn8 + 4] = wv1;
    __syncthreads();
#pragma unroll
    for (int cc = 0; cc < 32; ++cc) {
      float4 a = *(const float4*)&As[cc * 36 + r4];
      float2 w = *(const float2*)&Ws[cc * 68 + n2];
      acc[0][0] = fmaf(a.x, w.x, acc[0][0]); acc[0][1] = fmaf(a.x, w.y, acc[0][1]);
      acc[1][0] = fmaf(a.y, w.x, acc[1][0]); acc[1][1] = fmaf(a.y, w.y, acc[1][1]);
      acc[2][0] = fmaf(a.z, w.x, acc[2][0]); acc[2][1] = fmaf(a.z, w.y, acc[2][1]);
      acc[3][0] = fmaf(a.w, w.x, acc[3][0]); acc[3][1] = fmaf(a.w, w.y, acc[3][1]);
    }
  }
  float* dst; int nd;
  if (n0 < 128) { dst = a_arr; nd = n0; } else { dst = bb_arr; nd = n0 - 128; }
#pragma unroll
  for (int ri = 0; ri < 4; ++ri)
    *(float2*)&dst[(row0 + r4 + ri) * 128 + nd + n2] = make_float2(acc[ri][0], acc[ri][1]);
}

// -------------------------------------------------------------- wsplit ------
// wpk[L][n][k] = pack2(wL[k][n]); grid 192 x 256. Coalesced reads, scattered
// writes (192KB total, L2-absorbed).
__global__ __launch_bounds__(256) void wsplit_kernel(
    const float* __restrict__ w1, const float* __restrict__ w2,
    const float* __restrict__ w3, uint32_t* __restrict__ wpk)
{
  int e = blockIdx.x * 256 + threadIdx.x;   // 0..49151
  int L = e >> 14;
  int r = e & 16383;
  int k = r >> 7, n = r & 127;
  const float* w = (L == 0) ? w1 : (L == 1) ? w2 : w3;
  wpk[L * 16384 + n * 128 + k] = pack2(w[k * 128 + n]);
}

// ---------------------------------------------------------------- pair ------
// grid (64,16), 256 threads = 4 waves (2x2), LDS 66KB -> 2 blocks/CU.
__global__ __launch_bounds__(256) void pair_kernel(
    const float* __restrict__ a_arr, const float* __restrict__ bb_arr,
    const float* __restrict__ b0, const uint32_t* __restrict__ wpk,
    const float* __restrict__ b1, const float* __restrict__ b2,
    const float* __restrict__ b3,
    const float* __restrict__ mask, float* __restrict__ pmean)
{
  __shared__ uint32_t Apk[128 * 132];   // [r][k] packed (hi, lo*2048)
  int i = blockIdx.x, bp = blockIdx.y;
  int tid = threadIdx.x;

  // ---- init: p0 = leaky(a_i + bb_j + b0), packed into Apk ----
#pragma unroll 1
  for (int it = 0; it < 16; ++it) {
    int idx = it * 256 + tid;            // 0..4095 float4-groups
    int r   = idx >> 5;                  // 0..127
    int k4  = (idx & 31) * 4;
    int db  = r >> 6, j = r & 63;
    int bq  = bp * 2 + db;
    float4 av = *(const float4*)(a_arr + (i * BB + bq) * 128 + k4);
    float4 bv = *(const float4*)(bb_arr + (j * BB + bq) * 128 + k4);
    float4 zv = *(const float4*)(b0 + k4);
    uint4 w;
    w.x = pack2(leaky(av.x + bv.x + zv.x));
    w.y = pack2(leaky(av.y + bv.y + zv.y));
    w.z = pack2(leaky(av.z + bv.z + zv.z));
    w.w = pack2(leaky(av.w + bv.w + zv.w));
    *(uint4*)&Apk[r * 132 + k4] = w;
  }
  __syncthreads();

  int wid = __builtin_amdgcn_readfirstlane(tid >> 6);
  int wm = wid & 1, wn = wid >> 1;
  int lane = tid & 63;
  int m16 = lane & 15, q = lane >> 4;

  f32x4 hi[4][4], cr[4][4];

#pragma unroll 1
  for (int L = 0; L < 3; ++L) {
    const uint32_t* Wg = wpk + L * 16384;
    const float* Bv = (L == 0) ? b1 : (L == 1) ? b2 : b3;
#pragma unroll
    for (int mt = 0; mt < 4; ++mt)
#pragma unroll
      for (int nt = 0; nt < 4; ++nt) {
        hi[mt][nt] = (f32x4){0.f, 0.f, 0.f, 0.f};
        cr[mt][nt] = (f32x4){0.f, 0.f, 0.f, 0.f};
      }

#pragma unroll 1
    for (int ks = 0; ks < 4; ++ks) {
      int koff = ks * 32 + q * 8;
      F8u Wh[4], Wl[4];
#pragma unroll
      for (int nt = 0; nt < 4; ++nt) {
        const uint32_t* p = Wg + (wn * 64 + nt * 16 + m16) * 128 + koff;
        uint4 ra = *(const uint4*)p;
        uint4 rb = *(const uint4*)(p + 4);
        Wh[nt].u[0] = __builtin_amdgcn_perm(ra.y, ra.x, SEL_LO);
        Wh[nt].u[1] = __builtin_amdgcn_perm(ra.w, ra.z, SEL_LO);
        Wh[nt].u[2] = __builtin_amdgcn_perm(rb.y, rb.x, SEL_LO);
        Wh[nt].u[3] = __builtin_amdgcn_perm(rb.w, rb.z, SEL_LO);
        Wl[nt].u[0] = __builtin_amdgcn_perm(ra.y, ra.x, SEL_HI);
        Wl[nt].u[1] = __builtin_amdgcn_perm(ra.w, ra.z, SEL_HI);
        Wl[nt].u[2] = __builtin_amdgcn_perm(rb.y, rb.x, SEL_HI);
        Wl[nt].u[3] = __builtin_amdgcn_perm(rb.w, rb.z, SEL_HI);
      }
#pragma unroll
      for (int mt = 0; mt < 4; ++mt) {
        const uint32_t* ap = &Apk[(wm * 64 + mt * 16 + m16) * 132 + koff];
        uint4 ra = *(const uint4*)ap;
        uint4 rb = *(const uint4*)(ap + 4);
        F8u Ah, Al;
        Ah.u[0] = __builtin_amdgcn_perm(ra.y, ra.x, SEL_LO);
        Ah.u[1] = __builtin_amdgcn_perm(ra.w, ra.z, SEL_LO);
        Ah.u[2] = __builtin_amdgcn_perm(rb.y, rb.x, SEL_LO);
        Ah.u[3] = __builtin_amdgcn_perm(rb.w, rb.z, SEL_LO);
        Al.u[0] = __builtin_amdgcn_perm(ra.y, ra.x, SEL_HI);
        Al.u[1] = __builtin_amdgcn_perm(ra.w, ra.z, SEL_HI);
        Al.u[2] = __builtin_amdgcn_perm(rb.y, rb.x, SEL_HI);
        Al.u[3] = __builtin_amdgcn_perm(rb.w, rb.z, SEL_HI);
#pragma unroll
        for (int nt = 0; nt < 4; ++nt) {
          hi[mt][nt] = __builtin_amdgcn_mfma_f32_16x16x32_f16(
              Ah.h, Wh[nt].h, hi[mt][nt], 0, 0, 0);
          cr[mt][nt] = __builtin_amdgcn_mfma_f32_16x16x32_f16(
              Ah.h, Wl[nt].h, cr[mt][nt], 0, 0, 0);
          cr[mt][nt] = __builtin_amdgcn_mfma_f32_16x16x32_f16(
              Al.h, Wh[nt].h, cr[mt][nt], 0, 0, 0);
        }
      }
    }

    float bias[4];
#pragma unroll
    for (int nt = 0; nt < 4; ++nt) bias[nt] = Bv[wn * 64 + nt * 16 + m16];

    if (L < 2) {
      __syncthreads();                   // all reads of this layer's Apk done
#pragma unroll
      for (int mt = 0; mt < 4; ++mt)
#pragma unroll
        for (int nt = 0; nt < 4; ++nt)
#pragma unroll
          for (int rg = 0; rg < 4; ++rg) {
            float d = leaky(hi[mt][nt][rg] + cr[mt][nt][rg] * (1.0f / 2048.0f)
                            + bias[nt]);
            int row = wm * 64 + mt * 16 + q * 4 + rg;
            Apk[row * 132 + wn * 64 + nt * 16 + m16] = pack2(d);
          }
      __syncthreads();
    } else {
      float s[4] = {0.f, 0.f, 0.f, 0.f};
#pragma unroll
      for (int nt = 0; nt < 4; ++nt)
#pragma unroll
        for (int mt = 0; mt < 4; ++mt)
#pragma unroll
          for (int rg = 0; rg < 4; ++rg)
            s[nt] += leaky(hi[mt][nt][rg] + cr[mt][nt][rg] * (1.0f / 2048.0f)
                           + bias[nt]);
      int brow = i * BB + bp * 2 + wm;
      float mfac = (1.0f / 64.0f) * mask[brow];
#pragma unroll
      for (int nt = 0; nt < 4; ++nt) {
        s[nt] += __shfl_xor(s[nt], 16, 64);
        s[nt] += __shfl_xor(s[nt], 32, 64);
      }
      if (lane < 16) {
#pragma unroll
        for (int nt = 0; nt < 4; ++nt)
          pmean[brow * 128 + wn * 64 + nt * 16 + m16] = s[nt] * mfac;
      }
    }
  }
}

// ----------------------------------------------------------------- out ------
__global__ __launch_bounds__(256) void out_kernel(
    const float* __restrict__ pmean, const float* __restrict__ w4,
    const float* __restrict__ b4, const float* __restrict__ w5,
    const float* __restrict__ b5, const float* __restrict__ mask,
    float* __restrict__ out)
{
  __shared__ float Pm[16 * 132];
  __shared__ float T4[16 * 132];
  int bx = blockIdx.x;
  int col0 = (bx & 1) * 256;
  int row0 = (bx >> 1) * 16;
  int tid = threadIdx.x;
  int tr = tid >> 4, m = tid & 15;

  {
    const float* src = pmean + (row0 + tr) * 128 + 8 * m;
    *(float4*)&Pm[tr * 132 + 8 * m]     = *(const float4*)(src);
    *(float4*)&Pm[tr * 132 + 8 * m + 4] = *(const float4*)(src + 4);
  }
  __syncthreads();
  {
    int k8 = m * 8;
    float4 bv0 = *(const float4*)(b4 + k8);
    float4 bv1 = *(const float4*)(b4 + k8 + 4);
    float t[8] = {bv0.x, bv0.y, bv0.z, bv0.w, bv1.x, bv1.y, bv1.z, bv1.w};
#pragma unroll 4
    for (int cc = 0; cc < 128; ++cc) {
      float a = Pm[tr * 132 + cc];
      float4 w0v = *(const float4*)(w4 + cc * 128 + k8);
      float4 w1v = *(const float4*)(w4 + cc * 128 + k8 + 4);
      t[0] = fmaf(a, w0v.x, t[0]); t[1] = fmaf(a, w0v.y, t[1]);
      t[2] = fmaf(a, w0v.z, t[2]); t[3] = fmaf(a, w0v.w, t[3]);
      t[4] = fmaf(a, w1v.x, t[4]); t[5] = fmaf(a, w1v.y, t[5]);
      t[6] = fmaf(a, w1v.z, t[6]); t[7] = fmaf(a, w1v.w, t[7]);
    }
    *(float4*)&T4[tr * 132 + k8]     = make_float4(leaky(t[0]), leaky(t[1]), leaky(t[2]), leaky(t[3]));
    *(float4*)&T4[tr * 132 + k8 + 4] = make_float4(leaky(t[4]), leaky(t[5]), leaky(t[6]), leaky(t[7]));
  }
  __syncthreads();
  {
    int c16 = m * 16;
    const float* bsrc = b5 + col0 + c16;
    float o[16];
#pragma unroll
    for (int qq = 0; qq < 4; ++qq) {
      float4 bv = *(const float4*)(bsrc + 4 * qq);
      o[4*qq+0] = bv.x; o[4*qq+1] = bv.y; o[4*qq+2] = bv.z; o[4*qq+3] = bv.w;
    }
#pragma unroll 2
    for (int cc = 0; cc < 128; ++cc) {
      float a = T4[tr * 132 + cc];
      const float* wr = w5 + cc * 512 + col0 + c16;
#pragma unroll
      for (int qq = 0; qq < 4; ++qq) {
        float4 wv = *(const float4*)(wr + 4 * qq);
        o[4*qq+0] = fmaf(a, wv.x, o[4*qq+0]);
        o[4*qq+1] = fmaf(a, wv.y, o[4*qq+1]);
        o[4*qq+2] = fmaf(a, wv.z, o[4*qq+2]);
        o[4*qq+3] = fmaf(a, wv.w, o[4*qq+3]);
      }
    }
    float mv = mask[row0 + tr];
    float* dst = out + (row0 + tr) * 512 + col0 + c16;
#pragma unroll
    for (int qq = 0; qq < 4; ++qq)
      *(float4*)(dst + 4 * qq) = make_float4(leaky(o[4*qq+0]) * mv, leaky(o[4*qq+1]) * mv,
                                             leaky(o[4*qq+2]) * mv, leaky(o[4*qq+3]) * mv);
  }
}

// -------------------------------------------------------------- launch ------
extern "C" void kernel_launch(void* const* d_in, const int* in_sizes, int n_in,
                              void* d_out, int out_size, void* d_ws, size_t ws_size,
                              hipStream_t stream) {
  const float* x    = (const float*)d_in[0];
  const float* mask = (const float*)d_in[1];
  const float* cw0  = (const float*)d_in[2];
  // d_in[3] conv_b0: cancels in BN
  const float* g0   = (const float*)d_in[4];
  const float* be0  = (const float*)d_in[5];
  const float* cw1  = (const float*)d_in[6];
  // d_in[7] conv_b1: cancels in BN
  const float* g1   = (const float*)d_in[8];
  const float* be1  = (const float*)d_in[9];
  const float* w0   = (const float*)d_in[10];
  const float* b0   = (const float*)d_in[11];
  const float* w1   = (const float*)d_in[12];
  const float* b1   = (const float*)d_in[13];
  const float* w2   = (const float*)d_in[14];
  const float* b2   = (const float*)d_in[15];
  const float* w3   = (const float*)d_in[16];
  const float* b3   = (const float*)d_in[17];
  const float* w4   = (const float*)d_in[18];
  const float* b4   = (const float*)d_in[19];
  const float* w5   = (const float*)d_in[20];
  const float* b5   = (const float*)d_in[21];

  float* ws     = (float*)d_ws;
  float* yG     = ws;                    // 640*2048 = 1,310,720 words
  float* pmean  = ws;                    // overlays yG words [0, 262144)
  uint32_t* wpk = (uint32_t*)(ws + 262144);  // overlays yG words [262144, 311296)
  float* scale  = ws + 1310720;          // 384
  float* shift  = ws + 1311104;          // 384
  float* a_arr  = ws + 1311488;          // 2048*128
  float* bb_arr = ws + 1573632;          // 2048*128
  float* outp   = (float*)d_out;

  conv_kernel<<<320, 256, 0, stream>>>(x, mask, cw0, cw1, yG);
  stats_kernel<<<384, 256, 0, stream>>>(yG, g0, be0, g1, be1, scale, shift);
  ab_kernel<<<256, 256, 0, stream>>>(yG, scale, shift, mask, w0, a_arr, bb_arr);
  wsplit_kernel<<<192, 256, 0, stream>>>(w1, w2, w3, wpk);  // after ab: yG dead
  dim3 g5(64, 16);
  pair_kernel<<<g5, 256, 0, stream>>>(a_arr, bb_arr, b0, wpk, b1, b2, b3,
                                      mask, pmean);
  out_kernel<<<256, 256, 0, stream>>>(pmean, w4, b4, w5, b5, mask, outp);
}

// Round 7
// 285.672 us; speedup vs baseline: 1.4222x; 1.0346x over previous
//
#include <hip/hip_runtime.h>

// RelationLayer, round 7.
// R7: pair hot loop made perm-free. hi/lo fp16 planes stored SEPARATELY:
//   LDS Ahs/Als (f16, row stride 136 -> uint4 frag reads conflict-free and
//   16B-aligned), global Wh/Wl planes (wsplit). A/W fragments are direct 16B
//   loads feeding mfma_f32_16x16x32_f16 -- zero v_perm in the loop (R6 spent
//   ~768 perms/wave, VALUBusy 43%, MfmaUtil 14.7%).
// 512-thr blocks: 8 waves (2m x 4n), per wave 4mt x 2nt frags, acc = 64 VGPR.
// Next-ks W frags double-buffered in registers (hides L2 ~200cyc).
// Layer transition: lane-pair shfl_xor(1) + f16 pair pack -> 16 ds_write_b32
// per thread (vs 64 u16). Split: x = hi + lo/2048 (lo scaled into normal f16
// range); D = hi*wh + (hi*wl + lo*wh)/2048, lo*wl (~2^-22) dropped.
// conv/stats/ab/out unchanged from R4/R6 for attribution.

#define BB 32
#define CCH 384

__device__ __forceinline__ float leaky(float x) { return fmaxf(x, 0.1f * x); }

typedef _Float16 f16x8 __attribute__((ext_vector_type(8)));
typedef float f32x4 __attribute__((ext_vector_type(4)));

union F8 { uint4 q; f16x8 h; };
union H2 { _Float16 f[2]; uint32_t u; };

// split d into (hi, lo*2048) f16 pair-packed words
__device__ __forceinline__ void split2(float d0, float d1,
                                       uint32_t& hw, uint32_t& lw) {
  H2 h, l;
  h.f[0] = (_Float16)d0; h.f[1] = (_Float16)d1;
  l.f[0] = (_Float16)((d0 - (float)h.f[0]) * 2048.0f);
  l.f[1] = (_Float16)((d1 - (float)h.f[1]) * 2048.0f);
  hw = h.u; lw = l.u;
}

// ---------------------------------------------------------------- conv ------
__global__ __launch_bounds__(256) void conv_kernel(
    const float* __restrict__ x, const float* __restrict__ mask,
    const float* __restrict__ cw0, const float* __restrict__ cw1,
    float* __restrict__ yG)
{
  __shared__ float As[32 * 36];
  __shared__ float Ws[32 * 132];
  int bx = blockIdx.x;
  int rt = bx & 63;
  int ct = bx >> 6;
  int row0 = rt * 32;
  int tid = threadIdx.x;

  const float* wbase; int wstride;
  if (ct < 2) { wbase = cw0 + ct * 128 * 512; wstride = 512; }
  else        { wbase = cw1 + (ct - 2) * 512; wstride = 1536; }

  int sr  = tid >> 3;
  int sk4 = (tid & 7) * 4;
  const float* xrow = x + (row0 + sr) * 512;
  float mval = mask[row0 + sr];

  int r4 = (tid >> 5) * 4;
  int c4 = (tid & 31) * 4;

  float acc[4][4] = {{0.f,0.f,0.f,0.f},{0.f,0.f,0.f,0.f},
                     {0.f,0.f,0.f,0.f},{0.f,0.f,0.f,0.f}};
#pragma unroll 1
  for (int k0 = 0; k0 < 512; k0 += 32) {
    float4 xv = *(const float4*)(xrow + k0 + sk4);
    float4 wv[4];
#pragma unroll
    for (int rep = 0; rep < 4; ++rep) {
      int slot = rep * 256 + tid;
      int c = slot >> 3;
      int kq4 = (slot & 7) * 4;
      wv[rep] = *(const float4*)(wbase + c * wstride + k0 + kq4);
    }
    __syncthreads();
    As[(sk4 + 0) * 36 + sr] = xv.x * mval;
    As[(sk4 + 1) * 36 + sr] = xv.y * mval;
    As[(sk4 + 2) * 36 + sr] = xv.z * mval;
    As[(sk4 + 3) * 36 + sr] = xv.w * mval;
#pragma unroll
    for (int rep = 0; rep < 4; ++rep) {
      int slot = rep * 256 + tid;
      int c = slot >> 3;
      int kq4 = (slot & 7) * 4;
      Ws[(kq4 + 0) * 132 + c] = wv[rep].x;
      Ws[(kq4 + 1) * 132 + c] = wv[rep].y;
      Ws[(kq4 + 2) * 132 + c] = wv[rep].z;
      Ws[(kq4 + 3) * 132 + c] = wv[rep].w;
    }
    __syncthreads();
#pragma unroll
    for (int kk = 0; kk < 32; ++kk) {
      float4 a = *(const float4*)&As[kk * 36 + r4];
      float4 w = *(const float4*)&Ws[kk * 132 + c4];
      float av[4] = {a.x, a.y, a.z, a.w};
      float wv2[4] = {w.x, w.y, w.z, w.w};
#pragma unroll
      for (int ri = 0; ri < 4; ++ri)
#pragma unroll
        for (int ci = 0; ci < 4; ++ci)
          acc[ri][ci] = fmaf(av[ri], wv2[ci], acc[ri][ci]);
    }
  }
#pragma unroll
  for (int ci = 0; ci < 4; ++ci)
    *(float4*)&yG[(ct * 128 + c4 + ci) * 2048 + row0 + r4] =
        make_float4(acc[0][ci], acc[1][ci], acc[2][ci], acc[3][ci]);
}

// --------------------------------------------------------------- stats ------
__global__ __launch_bounds__(256) void stats_kernel(
    const float* __restrict__ yG,
    const float* __restrict__ g0, const float* __restrict__ be0,
    const float* __restrict__ g1, const float* __restrict__ be1,
    float* __restrict__ scale, float* __restrict__ shift)
{
  int c = blockIdx.x;
  int tid = threadIdx.x;
  float s = 0.f, s2 = 0.f;
  if (c < 256) {
    const float* src = yG + c * 2048 + tid * 8;
    float4 v0 = *(const float4*)(src);
    float4 v1 = *(const float4*)(src + 4);
    s  = v0.x + v0.y + v0.z + v0.w + v1.x + v1.y + v1.z + v1.w;
    s2 = v0.x*v0.x + v0.y*v0.y + v0.z*v0.z + v0.w*v0.w
       + v1.x*v1.x + v1.y*v1.y + v1.z*v1.z + v1.w*v1.w;
  } else {
    int cc = c - 256;
    const float* p0 = yG + (256 + cc) * 2048;
    const float* p1 = yG + (384 + cc) * 2048;
    const float* p2 = yG + (512 + cc) * 2048;
#pragma unroll
    for (int j = 0; j < 8; ++j) {
      int e = tid * 8 + j;
      float v = p1[e];
      if (e >= 32)   v += p0[e - 32];
      if (e < 2016)  v += p2[e + 32];
      s += v; s2 += v * v;
    }
  }
#pragma unroll
  for (int off = 32; off > 0; off >>= 1) {
    s  += __shfl_down(s, off);
    s2 += __shfl_down(s2, off);
  }
  __shared__ float rs[4], rs2[4];
  int wid = tid >> 6;
  if ((tid & 63) == 0) { rs[wid] = s; rs2[wid] = s2; }
  __syncthreads();
  if (tid == 0) {
    float S  = rs[0] + rs[1] + rs[2] + rs[3];
    float S2 = rs2[0] + rs2[1] + rs2[2] + rs2[3];
    float mean = S * (1.f / 2048.f);
    float var  = S2 * (1.f / 2048.f) - mean * mean;
    float g  = (c < 256) ? g0[c] : g1[c - 256];
    float be = (c < 256) ? be0[c] : be1[c - 256];
    float sc = g / sqrtf(var + 1e-5f);
    scale[c] = sc;
    shift[c] = be - mean * sc;
  }
}

// ------------------------------------------------------------------ ab ------
__global__ __launch_bounds__(256) void ab_kernel(
    const float* __restrict__ yG, const float* __restrict__ scale,
    const float* __restrict__ shift, const float* __restrict__ mask,
    const float* __restrict__ w0,
    float* __restrict__ a_arr, float* __restrict__ bb_arr)
{
  __shared__ float As[32 * 36];
  __shared__ float Ws[32 * 68];
  int bx = blockIdx.x;
  int rt = bx & 63, ct = bx >> 6;
  int row0 = rt * 32, n0 = ct * 64;
  int tid = threadIdx.x;
  int r4 = (tid >> 5) * 4;
  int n2 = (tid & 31) * 2;
  int scc = tid >> 3, srr4 = (tid & 7) * 4;
  int wnn8 = (tid & 7) * 8;
  const float* wbase = (n0 < 128) ? (w0 + n0) : (w0 + CCH * 128 + (n0 - 128));
  float4 mv = *(const float4*)(mask + row0 + srr4);

  float acc[4][2] = {{0.f, 0.f}};
#pragma unroll 1
  for (int c0 = 0; c0 < 384; c0 += 32) {
    int c = c0 + scc;
    float4 yv;
    if (c < 256) {
      yv = *(const float4*)(yG + c * 2048 + row0 + srr4);
    } else {
      int cc = c - 256;
      yv = *(const float4*)(yG + (384 + cc) * 2048 + row0 + srr4);
      if (rt > 0) {
        float4 u = *(const float4*)(yG + (256 + cc) * 2048 + row0 + srr4 - 32);
        yv.x += u.x; yv.y += u.y; yv.z += u.z; yv.w += u.w;
      }
      if (rt < 63) {
        float4 u = *(const float4*)(yG + (512 + cc) * 2048 + row0 + srr4 + 32);
        yv.x += u.x; yv.y += u.y; yv.z += u.z; yv.w += u.w;
      }
    }
    float sc = scale[c], sh = shift[c];
    float4 wv0 = *(const float4*)(wbase + c * 128 + wnn8);
    float4 wv1 = *(const float4*)(wbase + c * 128 + wnn8 + 4);
    __syncthreads();
    float4 hv;
    hv.x = leaky(fmaf(yv.x, sc, sh)) * mv.x;
    hv.y = leaky(fmaf(yv.y, sc, sh)) * mv.y;
    hv.z = leaky(fmaf(yv.z, sc, sh)) * mv.z;
    hv.w = leaky(fmaf(yv.w, sc, sh)) * mv.w;
    *(float4*)&As[scc * 36 + srr4] = hv;
    *(float4*)&Ws[scc * 68 + wnn8] = wv0;
    *(float4*)&Ws[scc * 68 + wnn8 + 4] = wv1;
    __syncthreads();
#pragma unroll
    for (int cc = 0; cc < 32; ++cc) {
      float4 a = *(const float4*)&As[cc * 36 + r4];
      float2 w = *(const float2*)&Ws[cc * 68 + n2];
      acc[0][0] = fmaf(a.x, w.x, acc[0][0]); acc[0][1] = fmaf(a.x, w.y, acc[0][1]);
      acc[1][0] = fmaf(a.y, w.x, acc[1][0]); acc[1][1] = fmaf(a.y, w.y, acc[1][1]);
      acc[2][0] = fmaf(a.z, w.x, acc[2][0]); acc[2][1] = fmaf(a.z, w.y, acc[2][1]);
      acc[3][0] = fmaf(a.w, w.x, acc[3][0]); acc[3][1] = fmaf(a.w, w.y, acc[3][1]);
    }
  }
  float* dst; int nd;
  if (n0 < 128) { dst = a_arr; nd = n0; } else { dst = bb_arr; nd = n0 - 128; }
#pragma unroll
  for (int ri = 0; ri < 4; ++ri)
    *(float2*)&dst[(row0 + r4 + ri) * 128 + nd + n2] = make_float2(acc[ri][0], acc[ri][1]);
}

// -------------------------------------------------------------- wsplit ------
// Wh plane: wpk[L*8192 + n*64 + k/2] (f16 pair along k); Wl at +24576 words.
// grid 96 x 256; coalesced reads (n fastest).
__global__ __launch_bounds__(256) void wsplit_kernel(
    const float* __restrict__ w1, const float* __restrict__ w2,
    const float* __restrict__ w3, uint32_t* __restrict__ wpk)
{
  int e = blockIdx.x * 256 + threadIdx.x;   // 0..24575 (L, k2, n)
  int L = e >> 13;
  int r = e & 8191;
  int k2 = r >> 7, n = r & 127;
  int k = k2 * 2;
  const float* w = (L == 0) ? w1 : (L == 1) ? w2 : w3;
  uint32_t hw, lw;
  split2(w[k * 128 + n], w[(k + 1) * 128 + n], hw, lw);
  wpk[L * 8192 + n * 64 + k2] = hw;
  wpk[24576 + L * 8192 + n * 64 + k2] = lw;
}

// ---------------------------------------------------------------- pair ------
// grid (64,16), 512 threads = 8 waves (2m x 4n). LDS 68KB.
// Ahs/Als: f16 planes as u32 words, row stride 68 words (136 f16).
__global__ __launch_bounds__(512) void pair_kernel(
    const float* __restrict__ a_arr, const float* __restrict__ bb_arr,
    const float* __restrict__ b0, const uint32_t* __restrict__ wpk,
    const float* __restrict__ b1, const float* __restrict__ b2,
    const float* __restrict__ b3,
    const float* __restrict__ mask, float* __restrict__ pmean)
{
  __shared__ uint32_t Ahs[128 * 68];
  __shared__ uint32_t Als[128 * 68];
  int i = blockIdx.x, bp = blockIdx.y;
  int tid = threadIdx.x;

  // ---- init: p0 = leaky(a_i + bb_j + b0) -> split planes ----
#pragma unroll 1
  for (int it = 0; it < 4; ++it) {
    int idx = it * 512 + tid;            // 0..2047
    int r   = idx >> 4;                  // 0..127
    int k8  = (idx & 15) * 8;
    int db  = r >> 6, j = r & 63;
    int bq  = bp * 2 + db;
    const float* ap = a_arr + (i * BB + bq) * 128 + k8;
    const float* bbp = bb_arr + (j * BB + bq) * 128 + k8;
    const float* zp = b0 + k8;
    float d[8];
#pragma unroll
    for (int t = 0; t < 8; t += 4) {
      float4 av = *(const float4*)(ap + t);
      float4 bv = *(const float4*)(bbp + t);
      float4 zv = *(const float4*)(zp + t);
      d[t+0] = leaky(av.x + bv.x + zv.x);
      d[t+1] = leaky(av.y + bv.y + zv.y);
      d[t+2] = leaky(av.z + bv.z + zv.z);
      d[t+3] = leaky(av.w + bv.w + zv.w);
    }
    uint4 hq, lq;
    split2(d[0], d[1], hq.x, lq.x);
    split2(d[2], d[3], hq.y, lq.y);
    split2(d[4], d[5], hq.z, lq.z);
    split2(d[6], d[7], hq.w, lq.w);
    *(uint4*)&Ahs[r * 68 + k8 / 2] = hq;
    *(uint4*)&Als[r * 68 + k8 / 2] = lq;
  }
  __syncthreads();

  int wid = __builtin_amdgcn_readfirstlane(tid >> 6);
  int wm = wid & 1, wn = wid >> 1;       // m-half, n-quarter
  int lane = tid & 63;
  int m16 = lane & 15, q = lane >> 4;

  f32x4 hi[4][2], cr[4][2];

#pragma unroll 1
  for (int L = 0; L < 3; ++L) {
    const uint32_t* WhL = wpk + L * 8192;
    const uint32_t* WlL = wpk + 24576 + L * 8192;
    const float* Bv = (L == 0) ? b1 : (L == 1) ? b2 : b3;
#pragma unroll
    for (int mt = 0; mt < 4; ++mt)
#pragma unroll
      for (int nt = 0; nt < 2; ++nt) {
        hi[mt][nt] = (f32x4){0.f, 0.f, 0.f, 0.f};
        cr[mt][nt] = (f32x4){0.f, 0.f, 0.f, 0.f};
      }

    // prefetch ks=0 W frags
    F8 Wh[2], Wl[2], Whn[2], Wln[2];
#pragma unroll
    for (int nt = 0; nt < 2; ++nt) {
      int wrow = wn * 32 + nt * 16 + m16;
      Wh[nt].q = *(const uint4*)(WhL + wrow * 64 + q * 4);
      Wl[nt].q = *(const uint4*)(WlL + wrow * 64 + q * 4);
    }

#pragma unroll 1
    for (int ks = 0; ks < 4; ++ks) {
      int koff2 = ks * 16 + q * 4;
      if (ks < 3) {
#pragma unroll
        for (int nt = 0; nt < 2; ++nt) {
          int wrow = wn * 32 + nt * 16 + m16;
          Whn[nt].q = *(const uint4*)(WhL + wrow * 64 + koff2 + 16);
          Wln[nt].q = *(const uint4*)(WlL + wrow * 64 + koff2 + 16);
        }
      }
#pragma unroll
      for (int mt = 0; mt < 4; ++mt) {
        int arow = wm * 64 + mt * 16 + m16;
        F8 Ah, Al;
        Ah.q = *(const uint4*)&Ahs[arow * 68 + koff2];
        Al.q = *(const uint4*)&Als[arow * 68 + koff2];
#pragma unroll
        for (int nt = 0; nt < 2; ++nt) {
          hi[mt][nt] = __builtin_amdgcn_mfma_f32_16x16x32_f16(
              Ah.h, Wh[nt].h, hi[mt][nt], 0, 0, 0);
          cr[mt][nt] = __builtin_amdgcn_mfma_f32_16x16x32_f16(
              Ah.h, Wl[nt].h, cr[mt][nt], 0, 0, 0);
          cr[mt][nt] = __builtin_amdgcn_mfma_f32_16x16x32_f16(
              Al.h, Wh[nt].h, cr[mt][nt], 0, 0, 0);
        }
      }
#pragma unroll
      for (int nt = 0; nt < 2; ++nt) { Wh[nt] = Whn[nt]; Wl[nt] = Wln[nt]; }
    }

    float bias[2];
#pragma unroll
    for (int nt = 0; nt < 2; ++nt) bias[nt] = Bv[wn * 32 + nt * 16 + m16];

    if (L < 2) {
      __syncthreads();                   // all frag reads of this layer done
      int par = lane & 1;
#pragma unroll
      for (int mt = 0; mt < 4; ++mt)
#pragma unroll
        for (int nt = 0; nt < 2; ++nt) {
          int colw = (wn * 32 + nt * 16 + (m16 & ~1)) >> 1;
#pragma unroll
          for (int rg = 0; rg < 4; ++rg) {
            float d = leaky(hi[mt][nt][rg] + cr[mt][nt][rg] * (1.0f / 2048.0f)
                            + bias[nt]);
            float dn = __shfl_xor(d, 1, 64);
            float de = par ? dn : d;     // even-col value
            float do_ = par ? d : dn;    // odd-col value
            uint32_t hw, lw;
            split2(de, do_, hw, lw);
            int row = wm * 64 + mt * 16 + q * 4 + rg;
            if (par) Als[row * 68 + colw] = lw;
            else     Ahs[row * 68 + colw] = hw;
          }
        }
      __syncthreads();
    } else {
      float s[2] = {0.f, 0.f};
#pragma unroll
      for (int nt = 0; nt < 2; ++nt)
#pragma unroll
        for (int mt = 0; mt < 4; ++mt)
#pragma unroll
          for (int rg = 0; rg < 4; ++rg)
            s[nt] += leaky(hi[mt][nt][rg] + cr[mt][nt][rg] * (1.0f / 2048.0f)
                           + bias[nt]);
      int brow = i * BB + bp * 2 + wm;
      float mfac = (1.0f / 64.0f) * mask[brow];
#pragma unroll
      for (int nt = 0; nt < 2; ++nt) {
        s[nt] += __shfl_xor(s[nt], 16, 64);
        s[nt] += __shfl_xor(s[nt], 32, 64);
      }
      if (lane < 16) {
#pragma unroll
        for (int nt = 0; nt < 2; ++nt)
          pmean[brow * 128 + wn * 32 + nt * 16 + m16] = s[nt] * mfac;
      }
    }
  }
}

// ----------------------------------------------------------------- out ------
__global__ __launch_bounds__(256) void out_kernel(
    const float* __restrict__ pmean, const float* __restrict__ w4,
    const float* __restrict__ b4, const float* __restrict__ w5,
    const float* __restrict__ b5, const float* __restrict__ mask,
    float* __restrict__ out)
{
  __shared__ float Pm[16 * 132];
  __shared__ float T4[16 * 132];
  int bx = blockIdx.x;
  int col0 = (bx & 1) * 256;
  int row0 = (bx >> 1) * 16;
  int tid = threadIdx.x;
  int tr = tid >> 4, m = tid & 15;

  {
    const float* src = pmean + (row0 + tr) * 128 + 8 * m;
    *(float4*)&Pm[tr * 132 + 8 * m]     = *(const float4*)(src);
    *(float4*)&Pm[tr * 132 + 8 * m + 4] = *(const float4*)(src + 4);
  }
  __syncthreads();
  {
    int k8 = m * 8;
    float4 bv0 = *(const float4*)(b4 + k8);
    float4 bv1 = *(const float4*)(b4 + k8 + 4);
    float t[8] = {bv0.x, bv0.y, bv0.z, bv0.w, bv1.x, bv1.y, bv1.z, bv1.w};
#pragma unroll 4
    for (int cc = 0; cc < 128; ++cc) {
      float a = Pm[tr * 132 + cc];
      float4 w0v = *(const float4*)(w4 + cc * 128 + k8);
      float4 w1v = *(const float4*)(w4 + cc * 128 + k8 + 4);
      t[0] = fmaf(a, w0v.x, t[0]); t[1] = fmaf(a, w0v.y, t[1]);
      t[2] = fmaf(a, w0v.z, t[2]); t[3] = fmaf(a, w0v.w, t[3]);
      t[4] = fmaf(a, w1v.x, t[4]); t[5] = fmaf(a, w1v.y, t[5]);
      t[6] = fmaf(a, w1v.z, t[6]); t[7] = fmaf(a, w1v.w, t[7]);
    }
    *(float4*)&T4[tr * 132 + k8]     = make_float4(leaky(t[0]), leaky(t[1]), leaky(t[2]), leaky(t[3]));
    *(float4*)&T4[tr * 132 + k8 + 4] = make_float4(leaky(t[4]), leaky(t[5]), leaky(t[6]), leaky(t[7]));
  }
  __syncthreads();
  {
    int c16 = m * 16;
    const float* bsrc = b5 + col0 + c16;
    float o[16];
#pragma unroll
    for (int qq = 0; qq < 4; ++qq) {
      float4 bv = *(const float4*)(bsrc + 4 * qq);
      o[4*qq+0] = bv.x; o[4*qq+1] = bv.y; o[4*qq+2] = bv.z; o[4*qq+3] = bv.w;
    }
#pragma unroll 2
    for (int cc = 0; cc < 128; ++cc) {
      float a = T4[tr * 132 + cc];
      const float* wr = w5 + cc * 512 + col0 + c16;
#pragma unroll
      for (int qq = 0; qq < 4; ++qq) {
        float4 wv = *(const float4*)(wr + 4 * qq);
        o[4*qq+0] = fmaf(a, wv.x, o[4*qq+0]);
        o[4*qq+1] = fmaf(a, wv.y, o[4*qq+1]);
        o[4*qq+2] = fmaf(a, wv.z, o[4*qq+2]);
        o[4*qq+3] = fmaf(a, wv.w, o[4*qq+3]);
      }
    }
    float mv = mask[row0 + tr];
    float* dst = out + (row0 + tr) * 512 + col0 + c16;
#pragma unroll
    for (int qq = 0; qq < 4; ++qq)
      *(float4*)(dst + 4 * qq) = make_float4(leaky(o[4*qq+0]) * mv, leaky(o[4*qq+1]) * mv,
                                             leaky(o[4*qq+2]) * mv, leaky(o[4*qq+3]) * mv);
  }
}

// -------------------------------------------------------------- launch ------
extern "C" void kernel_launch(void* const* d_in, const int* in_sizes, int n_in,
                              void* d_out, int out_size, void* d_ws, size_t ws_size,
                              hipStream_t stream) {
  const float* x    = (const float*)d_in[0];
  const float* mask = (const float*)d_in[1];
  const float* cw0  = (const float*)d_in[2];
  // d_in[3] conv_b0: cancels in BN
  const float* g0   = (const float*)d_in[4];
  const float* be0  = (const float*)d_in[5];
  const float* cw1  = (const float*)d_in[6];
  // d_in[7] conv_b1: cancels in BN
  const float* g1   = (const float*)d_in[8];
  const float* be1  = (const float*)d_in[9];
  const float* w0   = (const float*)d_in[10];
  const float* b0   = (const float*)d_in[11];
  const float* w1   = (const float*)d_in[12];
  const float* b1   = (const float*)d_in[13];
  const float* w2   = (const float*)d_in[14];
  const float* b2   = (const float*)d_in[15];
  const float* w3   = (const float*)d_in[16];
  const float* b3   = (const float*)d_in[17];
  const float* w4   = (const float*)d_in[18];
  const float* b4   = (const float*)d_in[19];
  const float* w5   = (const float*)d_in[20];
  const float* b5   = (const float*)d_in[21];

  float* ws     = (float*)d_ws;
  float* yG     = ws;                    // 640*2048 = 1,310,720 words
  float* pmean  = ws;                    // overlays yG words [0, 262144)
  uint32_t* wpk = (uint32_t*)(ws + 262144);  // overlays yG [262144, 311296)
  float* scale  = ws + 1310720;          // 384
  float* shift  = ws + 1311104;          // 384
  float* a_arr  = ws + 1311488;          // 2048*128
  float* bb_arr = ws + 1573632;          // 2048*128
  float* outp   = (float*)d_out;

  conv_kernel<<<320, 256, 0, stream>>>(x, mask, cw0, cw1, yG);
  stats_kernel<<<384, 256, 0, stream>>>(yG, g0, be0, g1, be1, scale, shift);
  ab_kernel<<<256, 256, 0, stream>>>(yG, scale, shift, mask, w0, a_arr, bb_arr);
  wsplit_kernel<<<96, 256, 0, stream>>>(w1, w2, w3, wpk);  // after ab: yG dead
  dim3 g5(64, 16);
  pair_kernel<<<g5, 512, 0, stream>>>(a_arr, bb_arr, b0, wpk, b1, b2, b3,
                                      mask, pmean);
  out_kernel<<<256, 256, 0, stream>>>(pmean, w4, b4, w5, b5, mask, outp);
}